// Round 5
// baseline (213.805 us; speedup 1.0000x reference)
//
#include <hip/hip_runtime.h>

// Head: fused single-head causal attention. Round 5:
//  - 2 batches per wave (grid 2048, 64-thr blocks): exactly 8 resident
//    one-wave blocks/CU, zero serial occupancy rounds; batch b1's x-tiles
//    load during batch b0's compute tail (cross-batch pipelining).
//  - softmax row-sum via MFMA (P_hat @ Ones as a 3rd accumulator): every
//    lane receives its row's sum in C-layout; normalize O at the store.
//    No ds_swizzle reduction chains remain.
//  - weights register-resident (24 B-frags), scale folded into Wq, no
//    max-subtraction (|s| <= ~2 analytically; validated R4 absmax).
//
// mfma_f32_16x16x32_bf16 layouts (HW-verified, guide §3):
//   A-frag: A[m = lane&15][k = quad*8 + j]
//   B-frag: B[k = quad*8 + j][n = lane&15]
//   C/D   : col = lane&15, row = quad*4 + reg

#define TT 64
#define CC 128
#define HD 32

typedef __bf16 bf16_t;
typedef __bf16 bf8_t __attribute__((ext_vector_type(8)));
typedef __bf16 bf4_t __attribute__((ext_vector_type(4)));
typedef float  f4_t  __attribute__((ext_vector_type(4)));

// d_ws: wf[(n6*4 + kk)*64 + lane] = 16-byte bf8 B-frag.
// n6 = 0..5 (q lo/hi, k lo/hi, v lo/hi), kk = 0..3 (K blocks of 32).
// Element j = Wsel[(kk*32 + (lane>>4)*8 + j)][(n6&1)*16 + (lane&15)].
// Q-frags (n6<2) pre-scaled by 1/sqrt(32).
__global__ __launch_bounds__(256) void prep_weights(
    const float* __restrict__ Wq, const float* __restrict__ Wk,
    const float* __restrict__ Wv, bf16_t* __restrict__ wf)
{
  int t = blockIdx.x * 256 + threadIdx.x;   // 0..12287
  int j    = t & 7;
  int lane = (t >> 3) & 63;
  int kt   = (t >> 9) & 3;
  int n6   = t >> 11;
  int k    = kt * 32 + (lane >> 4) * 8 + j;
  int col  = (n6 & 1) * 16 + (lane & 15);
  const float* W = (n6 >> 1) == 0 ? Wq : ((n6 >> 1) == 1 ? Wk : Wv);
  float v = W[k * HD + col];
  if (n6 < 2) v *= 0.17677669529663687f;    // fold 1/sqrt(32) into Wq
  wf[t] = (bf16_t)v;
}

__global__ __launch_bounds__(64, 2) void head_fused(
    const float* __restrict__ x, const bf8_t* __restrict__ wf,
    float* __restrict__ out)
{
  __shared__ __align__(16) bf16_t qs[TT][40];   // q[row][d]        5120 B
  __shared__ __align__(16) bf16_t ks[TT][40];   // k[row][d]        5120 B
  __shared__ __align__(16) bf16_t vt[HD][72];   // v^T[d][row]      4608 B
  __shared__ __align__(16) bf16_t ps[16][72];   // P_hat strip      2304 B
  // total 17152 B; 8 one-wave blocks/CU (VGPR-capped at 2 waves/EU)

  const int lane = threadIdx.x;      // 0..63, one wave
  const int quad = lane >> 4;
  const int l16  = lane & 15;
  const size_t b0 = (size_t)blockIdx.x * 2;    // this wave's two batches
  const float* __restrict__ xb[2] = { x + b0 * (TT * CC), x + (b0 + 1) * (TT * CC) };
  float* __restrict__ ob[2] = { out + b0 * (TT * HD), out + (b0 + 1) * (TT * HD) };

  const f4_t zero4 = {0.f, 0.f, 0.f, 0.f};
  const bf8_t ones = { (bf16_t)1.f, (bf16_t)1.f, (bf16_t)1.f, (bf16_t)1.f,
                       (bf16_t)1.f, (bf16_t)1.f, (bf16_t)1.f, (bf16_t)1.f };

  bf8_t wfr[24];                     // register-resident weight B-frags (96 VGPR)

  // issue one x-tile's loads: 8x dwordx4 (lane covers 32 B of row l16)
  auto load_tile = [&](float4* d, int bb, int i) {
    #pragma unroll
    for (int kk = 0; kk < 4; ++kk) {
      const float* s = xb[bb] + (16 * i + l16) * CC + kk * 32 + quad * 8;
      d[2 * kk]     = *(const float4*)s;
      d[2 * kk + 1] = *(const float4*)(s + 4);
    }
  };

  auto proj_tile = [&](const float4* d, int i) {
    f4_t acc[6];
    #pragma unroll
    for (int n = 0; n < 6; ++n) acc[n] = zero4;
    #pragma unroll
    for (int kk = 0; kk < 4; ++kk) {
      float4 f0 = d[2 * kk], f1 = d[2 * kk + 1];
      bf8_t a;
      a[0] = (bf16_t)f0.x; a[1] = (bf16_t)f0.y; a[2] = (bf16_t)f0.z; a[3] = (bf16_t)f0.w;
      a[4] = (bf16_t)f1.x; a[5] = (bf16_t)f1.y; a[6] = (bf16_t)f1.z; a[7] = (bf16_t)f1.w;
      #pragma unroll
      for (int n = 0; n < 6; ++n)
        acc[n] = __builtin_amdgcn_mfma_f32_16x16x32_bf16(a, wfr[n * 4 + kk], acc[n], 0, 0, 0);
    }
    #pragma unroll
    for (int r = 0; r < 4; ++r) {
      int row = 16 * i + quad * 4 + r;         // C/D: row = quad*4 + reg
      qs[row][l16]      = (bf16_t)acc[0][r];
      qs[row][16 + l16] = (bf16_t)acc[1][r];
      ks[row][l16]      = (bf16_t)acc[2][r];
      ks[row][16 + l16] = (bf16_t)acc[3][r];
    }
    bf4_t v0 = { (bf16_t)acc[4][0], (bf16_t)acc[4][1], (bf16_t)acc[4][2], (bf16_t)acc[4][3] };
    bf4_t v1 = { (bf16_t)acc[5][0], (bf16_t)acc[5][1], (bf16_t)acc[5][2], (bf16_t)acc[5][3] };
    *(bf4_t*)&vt[l16][16 * i + quad * 4]      = v0;   // tokens quad*4..+3 contiguous
    *(bf4_t*)&vt[16 + l16][16 * i + quad * 4] = v1;
  };

  // scores -> exp -> P_hat -> (PV + MFMA row-sum) -> normalized store
  auto phase2 = [&](float* obase) {
    #pragma unroll
    for (int i = 0; i < 4; ++i) {
      f4_t sc[4];
      bf8_t aq = *(const bf8_t*)&qs[16 * i + l16][quad * 8];   // scale pre-folded
      #pragma unroll
      for (int j = 0; j < 4; ++j) {
        sc[j] = zero4;
        if (j <= i) {                          // wave-uniform
          bf8_t bk = *(const bf8_t*)&ks[16 * j + l16][quad * 8];
          sc[j] = __builtin_amdgcn_mfma_f32_16x16x32_bf16(aq, bk, zero4, 0, 0, 0);
        }
      }
      #pragma unroll
      for (int r = 0; r < 4; ++r) {
        int rl = quad * 4 + r;
        #pragma unroll
        for (int j = 0; j < 4; ++j) {
          if (j <= i) {
            bool valid = (j < i) | (l16 <= rl);          // diagonal causal mask
            float e = valid ? __expf(sc[j][r]) : 0.f;    // no max-sub: |s| small
            ps[rl][j * 16 + l16] = (bf16_t)e;
          } else if (j == (i | 1)) {
            ps[rl][j * 16 + l16] = (bf16_t)0.f;          // zero-fill read range (even i)
          }
        }
      }
      f4_t o0 = zero4, o1 = zero4, rs = zero4;
      #pragma unroll
      for (int kk = 0; kk <= (i >> 1); ++kk) { // skip all-zero K-tiles for i<2
        int k0 = kk * 32 + quad * 8;
        bf8_t ap  = *(const bf8_t*)&ps[l16][k0];
        bf8_t bv0 = *(const bf8_t*)&vt[l16][k0];
        bf8_t bv1 = *(const bf8_t*)&vt[16 + l16][k0];
        o0 = __builtin_amdgcn_mfma_f32_16x16x32_bf16(ap, bv0, o0, 0, 0, 0);
        o1 = __builtin_amdgcn_mfma_f32_16x16x32_bf16(ap, bv1, o1, 0, 0, 0);
        rs = __builtin_amdgcn_mfma_f32_16x16x32_bf16(ap, ones, rs, 0, 0, 0);  // row-sum
      }
      #pragma unroll
      for (int r = 0; r < 4; ++r) {
        float inv = __builtin_amdgcn_rcpf(rs[r]);        // psum > 0 (diagonal survives)
        int row = 16 * i + quad * 4 + r;
        obase[row * HD + l16]      = o0[r] * inv;
        obase[row * HD + 16 + l16] = o1[r] * inv;
      }
    }
  };

  // ---------------- pipelined schedule over 2 batches ----------------
  float4 ta[8], tb[8];
  load_tile(ta, 0, 0);
  #pragma unroll
  for (int t = 0; t < 24; ++t) wfr[t] = wf[t * 64 + lane];   // L2-hot
  load_tile(tb, 0, 1);
  proj_tile(ta, 0);
  load_tile(ta, 0, 2);
  proj_tile(tb, 1);
  load_tile(tb, 0, 3);
  proj_tile(ta, 2);
  load_tile(ta, 1, 0);               // batch 1 prefetch starts
  proj_tile(tb, 3);
  load_tile(tb, 1, 1);
  phase2(ob[0]);                     // b1 tiles 0-1 in flight under this tail
  proj_tile(ta, 0);
  load_tile(ta, 1, 2);
  proj_tile(tb, 1);
  load_tile(tb, 1, 3);
  proj_tile(ta, 2);
  proj_tile(tb, 3);
  phase2(ob[1]);
}

extern "C" void kernel_launch(void* const* d_in, const int* in_sizes, int n_in,
                              void* d_out, int out_size, void* d_ws, size_t ws_size,
                              hipStream_t stream) {
  const float* x  = (const float*)d_in[0];
  const float* Wq = (const float*)d_in[1];
  const float* Wk = (const float*)d_in[2];
  const float* Wv = (const float*)d_in[3];
  float* out = (float*)d_out;
  bf16_t* wf = (bf16_t*)d_ws;                  // 12288 bf16 = 24 KB
  int B = in_sizes[0] / (TT * CC);             // 4096
  int nblk = B / 2;                            // 2 batches per wave

  prep_weights<<<dim3(48), dim3(256), 0, stream>>>(Wq, Wk, Wv, wf);
  head_fused<<<dim3(nblk), dim3(64), 0, stream>>>(x, (const bf8_t*)wf, out);
}